// Round 7
// baseline (149.766 us; speedup 1.0000x reference)
//
#include <hip/hip_runtime.h>
#include <math.h>

typedef __attribute__((ext_vector_type(8))) short  short8;    // 8 bf16 = 4 VGPRs
typedef __attribute__((ext_vector_type(4))) float  floatx4;   // MFMA C/D

#define MFMA16(a, b, c) __builtin_amdgcn_mfma_f32_16x16x32_bf16(a, b, c, 0, 0, 0)

constexpr int NSEQ = 2048;
constexpr int DIN  = 768;
constexpr int NH   = 12;
constexpr float QSCALE = 0.18033688011112042f;  // log2(e)/8

// Pitch 72 shorts = 144 B rows (16 B-aligned for b128). Read patterns on this
// pitch are uniform-8 (benign); the only 16-way offender was the Ks staging
// WRITE pattern — eliminated this round by keeping K in registers.
constexpr int PK = 72;

__device__ __forceinline__ ushort f2bf(float f) {   // RNE fp32 -> bf16
    unsigned u = __float_as_uint(f);
    u += 0x7FFF + ((u >> 16) & 1);
    return (ushort)(u >> 16);
}
__device__ __forceinline__ float bf2f(ushort u) {
    return __uint_as_float(((unsigned)u) << 16);
}
__device__ __forceinline__ unsigned cvt_pk_bf16(float lo, float hi) {
    unsigned r;
    asm("v_cvt_pk_bf16_f32 %0, %1, %2" : "=v"(r) : "v"(lo), "v"(hi));
    return r;
}
// pack 8 f32 -> 8 bf16 (RNE) with 4 instructions
__device__ __forceinline__ short8 pk8(float4 a, float4 b) {
    union { unsigned u[4]; short8 s; } r;
    r.u[0] = cvt_pk_bf16(a.x, a.y);
    r.u[1] = cvt_pk_bf16(a.z, a.w);
    r.u[2] = cvt_pk_bf16(b.x, b.y);
    r.u[3] = cvt_pk_bf16(b.z, b.w);
    return r.s;
}
// LDS-only barrier: orders ds ops across the block WITHOUT draining vmcnt,
// so register-prefetch global loads stay in flight across the barrier.
__device__ __forceinline__ void bar_lds() {
    asm volatile("s_waitcnt lgkmcnt(0)" ::: "memory");
    __builtin_amdgcn_s_barrier();
}

// -----------------------------------------------------------------------------
// Kernel 1: h = x @ Wq^T with FUSED f32->bf16 conversion (round-6 verified).
// BM=64 x BN=64, grid (64,12) = 768 blocks, 3/CU. Staging loads are f32
// float4 pairs, converted via v_cvt_pk_bf16_f32 at LDS-write time.
// -----------------------------------------------------------------------------
__global__ __launch_bounds__(256, 3)
void qkv_mfma(const float* __restrict__ x, const float* __restrict__ Wq,
              ushort* __restrict__ h)
{
    __shared__ ushort As[64 * PK];    // [row][k]
    __shared__ ushort Bs[64 * PK];    // [col][k]

    const int tid  = threadIdx.x;
    const int w    = tid >> 6;
    const int lane = tid & 63;
    const int m    = lane & 15;
    const int quad = lane >> 4;
    const int r0   = blockIdx.x * 64;
    const int c0   = blockIdx.y * 64;
    const int mrow0 = (w & 1) * 32;
    const int ncol0 = (w >> 1) * 32;

    floatx4 C[2][2] = {};
    float4 arf[2][2], brf[2][2];      // f32 prefetch (8 floats per id)

    #pragma unroll
    for (int i = 0; i < 2; ++i) {
        int id = tid + i * 256;
        const float* ax = x  + (size_t)(r0 + (id >> 3)) * DIN + (id & 7) * 8;
        const float* bx = Wq + (size_t)(c0 + (id >> 3)) * DIN + (id & 7) * 8;
        arf[i][0] = ((const float4*)ax)[0]; arf[i][1] = ((const float4*)ax)[1];
        brf[i][0] = ((const float4*)bx)[0]; brf[i][1] = ((const float4*)bx)[1];
    }

    for (int kk = 0; kk < 12; ++kk) {
        bar_lds();                      // prior reads consumed; no vmcnt drain
        #pragma unroll
        for (int i = 0; i < 2; ++i) {
            int id = tid + i * 256;
            *(short8*)&As[(id >> 3) * PK + (id & 7) * 8] = pk8(arf[i][0], arf[i][1]);
            *(short8*)&Bs[(id >> 3) * PK + (id & 7) * 8] = pk8(brf[i][0], brf[i][1]);
        }
        if (kk < 11) {                  // prefetch next tile (stays in flight)
            const int k0 = (kk + 1) * 64;
            #pragma unroll
            for (int i = 0; i < 2; ++i) {
                int id = tid + i * 256;
                const float* ax = x  + (size_t)(r0 + (id >> 3)) * DIN + k0 + (id & 7) * 8;
                const float* bx = Wq + (size_t)(c0 + (id >> 3)) * DIN + k0 + (id & 7) * 8;
                arf[i][0] = ((const float4*)ax)[0]; arf[i][1] = ((const float4*)ax)[1];
                brf[i][0] = ((const float4*)bx)[0]; brf[i][1] = ((const float4*)bx)[1];
            }
        }
        bar_lds();                      // writes visible; loads NOT drained

        #pragma unroll
        for (int kt2 = 0; kt2 < 2; ++kt2) {
            short8 a0 = *(const short8*)&As[(mrow0 + m)      * PK + kt2 * 32 + quad * 8];
            short8 a1 = *(const short8*)&As[(mrow0 + 16 + m) * PK + kt2 * 32 + quad * 8];
            short8 b0 = *(const short8*)&Bs[(ncol0 + m)      * PK + kt2 * 32 + quad * 8];
            short8 b1 = *(const short8*)&Bs[(ncol0 + 16 + m) * PK + kt2 * 32 + quad * 8];
            C[0][0] = MFMA16(a0, b0, C[0][0]);
            C[0][1] = MFMA16(a0, b1, C[0][1]);
            C[1][0] = MFMA16(a1, b0, C[1][0]);
            C[1][1] = MFMA16(a1, b1, C[1][1]);
        }
    }

    #pragma unroll
    for (int mt = 0; mt < 2; ++mt)
        #pragma unroll
        for (int nt = 0; nt < 2; ++nt) {
            int cg = c0 + ncol0 + nt * 16 + m;
            int head = cg >> 6, d = cg & 63;
            #pragma unroll
            for (int r = 0; r < 4; ++r) {
                int rg = r0 + mrow0 + mt * 16 + quad * 4 + r;
                int b = rg >> 11, q = rg & 2047;
                h[((size_t)(b * NH + head) * NSEQ + q) * 64 + d] = f2bf(C[mt][nt][r]);
            }
        }
}

// -----------------------------------------------------------------------------
// Kernel 2: causal flash attention. Round-1 proven skeleton (grid (64,24),
// 16 q/wave, 2-wave blocks = 3 waves/SIMD, cooperative Vt staging, bar_lds)
// with ONE change: K fragments in REGISTERS, loaded direct from global with a
// one-tile-ahead prefetch (issued after tile k's S-MFMAs, consumed after
// stage+softmax+barrier+PV ≈ 500+ cy -> L2 latency hidden). This deletes Ks:
// -4 b128 writes (the 16-way-conflict offender, r6 counter-verified) and
// -8 b128 reads per wave-tile, and S-MFMA becomes LDS-independent.
// -----------------------------------------------------------------------------
__global__ __launch_bounds__(128, 3)
void attn_mfma(const ushort* __restrict__ h, float* __restrict__ out)
{
    __shared__ ushort Vt[64 * PK];      // [d][key]
    __shared__ ushort Ps[2 * 16 * PK];  // per-wave P [q][key]

    const int tid  = threadIdx.x;
    const int w    = tid >> 6;          // 0..1
    const int lane = tid & 63;
    const int m    = lane & 15;
    const int quad = lane >> 4;

    const int xi = blockIdx.x;          // 0..63
    const int bh = blockIdx.y;          // 0..23
    const int t  = bh >> 2;
    const int qt = (t & 1) ? xi : (63 - xi);   // per-CU heavy/light alternation
    const int q0 = qt * 32;
    const int wq = q0 + w * 16;         // this wave's q base
    const int nkt = (qt >> 1) + 1;      // # of 64-key tiles
    const ushort* __restrict__ Hh = h + (size_t)bh * NSEQ * 64;
    ushort* Psw = Ps + w * 16 * PK;

    const int kr2  = (tid & 31) * 2;    // V staging: 2 adjacent key rows
    const int part = tid >> 5;          // d-chunk 0..3 (16 d each)
    const int db   = part * 16;

    // Q fragments (B-operand: n=q=m, k=d), pre-scaled by log2(e)/8
    short8 qa[2];
    #pragma unroll
    for (int kt2 = 0; kt2 < 2; ++kt2) {
        short8 raw = *(const short8*)(Hh + (size_t)(wq + m) * 64 + kt2 * 32 + quad * 8);
        #pragma unroll
        for (int j = 0; j < 8; ++j)
            qa[kt2][j] = (short)f2bf(bf2f((ushort)raw[j]) * QSCALE);
    }

    floatx4 O[4] = {};                  // O^T tiles: d = mt*16+quad*4+r, q = m
    float lacc = 0.0f;

    // K fragments in registers (A-operand: row=key=mt*16+m, col=kt2*32+quad*8)
    short8 kf[2][4];
    #pragma unroll
    for (int kt2 = 0; kt2 < 2; ++kt2)
        #pragma unroll
        for (int mt = 0; mt < 4; ++mt)
            kf[kt2][mt] = *(const short8*)(Hh + (size_t)(mt * 16 + m) * 64 + kt2 * 32 + quad * 8);

    short8 pre[4];                      // prefetched V rows kr2, kr2+1
    {
        const ushort* src = Hh + (size_t)kr2 * 64 + db;
        pre[0] = *(const short8*)src;
        pre[1] = *(const short8*)(src + 8);
        pre[2] = *(const short8*)(src + 64);
        pre[3] = *(const short8*)(src + 72);
    }

    for (int kt = 0; kt < nkt; ++kt) {
        // ---- S^T = K Q^T : pure registers, no LDS dependency ----
        floatx4 S[4] = {};
        #pragma unroll
        for (int kt2 = 0; kt2 < 2; ++kt2)
            #pragma unroll
            for (int mt = 0; mt < 4; ++mt)
                S[mt] = MFMA16(kf[kt2][mt], qa[kt2], S[mt]);

        if (kt + 1 < nkt) {             // prefetch next K tile into registers
            const ushort* Kg = Hh + (size_t)(kt + 1) * 64 * 64;
            #pragma unroll
            for (int kt2 = 0; kt2 < 2; ++kt2)
                #pragma unroll
                for (int mt = 0; mt < 4; ++mt)
                    kf[kt2][mt] = *(const short8*)(Kg + (size_t)(mt * 16 + m) * 64 + kt2 * 32 + quad * 8);
        }

        bar_lds();                      // prev PV done reading Vt (no vmcnt drain)

        // ---- stage V^T (packed key-pairs per dword; ~2-way = free) ----
        union { short8 v; ushort u[8]; } a0, a1, b0, b1;
        a0.v = pre[0]; a1.v = pre[1]; b0.v = pre[2]; b1.v = pre[3];
        #pragma unroll
        for (int i = 0; i < 8; ++i) {
            *(unsigned*)&Vt[(db + i)     * PK + kr2] = (unsigned)a0.u[i] | ((unsigned)b0.u[i] << 16);
            *(unsigned*)&Vt[(db + 8 + i) * PK + kr2] = (unsigned)a1.u[i] | ((unsigned)b1.u[i] << 16);
        }
        if (kt + 1 < nkt) {             // prefetch next V tile (stays in flight)
            const ushort* src = Hh + (size_t)((kt + 1) * 64 + kr2) * 64 + db;
            pre[0] = *(const short8*)src;
            pre[1] = *(const short8*)(src + 8);
            pre[2] = *(const short8*)(src + 64);
            pre[3] = *(const short8*)(src + 72);
        }

        // ---- exp2 + packed P write (cvt_pk) + l accumulate ----
        const int lim = wq + m - kt * 64;   // causal limit in-tile
        if (kt == nkt - 1) {                // diagonal tile: causal mask
            #pragma unroll
            for (int mt = 0; mt < 4; ++mt) {
                float p0 = (mt * 16 + quad * 4 + 0 <= lim) ? exp2f(S[mt][0]) : 0.0f;
                float p1 = (mt * 16 + quad * 4 + 1 <= lim) ? exp2f(S[mt][1]) : 0.0f;
                float p2 = (mt * 16 + quad * 4 + 2 <= lim) ? exp2f(S[mt][2]) : 0.0f;
                float p3 = (mt * 16 + quad * 4 + 3 <= lim) ? exp2f(S[mt][3]) : 0.0f;
                lacc += (p0 + p1) + (p2 + p3);
                uint2 pw;
                pw.x = cvt_pk_bf16(p0, p1);
                pw.y = cvt_pk_bf16(p2, p3);
                *(uint2*)&Psw[m * PK + mt * 16 + quad * 4] = pw;
            }
        } else {                            // interior tile: no mask
            #pragma unroll
            for (int mt = 0; mt < 4; ++mt) {
                float p0 = exp2f(S[mt][0]);
                float p1 = exp2f(S[mt][1]);
                float p2 = exp2f(S[mt][2]);
                float p3 = exp2f(S[mt][3]);
                lacc += (p0 + p1) + (p2 + p3);
                uint2 pw;
                pw.x = cvt_pk_bf16(p0, p1);
                pw.y = cvt_pk_bf16(p2, p3);
                *(uint2*)&Psw[m * PK + mt * 16 + quad * 4] = pw;
            }
        }

        bar_lds();                      // Vt writes visible to both waves

        // ---- O^T += V^T P^T (Vt cross-wave, Ps same-wave) ----
        #pragma unroll
        for (int kt2 = 0; kt2 < 2; ++kt2) {
            short8 pb = *(const short8*)&Psw[m * PK + kt2 * 32 + quad * 8];
            #pragma unroll
            for (int mt = 0; mt < 4; ++mt) {
                short8 va = *(const short8*)&Vt[(mt * 16 + m) * PK + kt2 * 32 + quad * 8];
                O[mt] = MFMA16(va, pb, O[mt]);
            }
        }
    }

    // ---- l reduce across the 4 quads holding the same q ----
    lacc += __shfl_xor(lacc, 16);
    lacc += __shfl_xor(lacc, 32);
    float linv = 1.0f / lacc;

    // ---- store out[bh][d][q] (reference's transposed layout) ----
    #pragma unroll
    for (int mt = 0; mt < 4; ++mt)
        #pragma unroll
        for (int r = 0; r < 4; ++r) {
            int d = mt * 16 + quad * 4 + r;
            out[((size_t)bh * 64 + d) * NSEQ + q0 + w * 16 + m] = O[mt][r] * linv;
        }
}

extern "C" void kernel_launch(void* const* d_in, const int* in_sizes, int n_in,
                              void* d_out, int out_size, void* d_ws, size_t ws_size,
                              hipStream_t stream)
{
    (void)in_sizes; (void)n_in; (void)out_size; (void)ws_size;
    const float* x  = (const float*)d_in[0];
    const float* Wq = (const float*)d_in[1];
    float* out = (float*)d_out;

    ushort* hb = (ushort*)d_ws;                 // 6.29 MB (ws is 256 MiB)

    qkv_mfma<<<dim3(64, 12), dim3(256), 0, stream>>>(x, Wq, hb);
    attn_mfma<<<dim3(64, 24), dim3(128), 0, stream>>>(hb, out);
}

// Round 8
// 120.152 us; speedup vs baseline: 1.2465x; 1.2465x over previous
//
#include <hip/hip_runtime.h>
#include <math.h>

typedef __attribute__((ext_vector_type(8))) short  short8;    // 8 bf16 = 4 VGPRs
typedef __attribute__((ext_vector_type(4))) float  floatx4;   // MFMA C/D

#define MFMA16(a, b, c) __builtin_amdgcn_mfma_f32_16x16x32_bf16(a, b, c, 0, 0, 0)

constexpr int NSEQ = 2048;
constexpr int DIN  = 768;
constexpr int NH   = 12;
constexpr float QSCALE = 0.18033688011112042f;  // log2(e)/8

// Pitch 72 shorts = 144 B rows: 16 B-aligned for b128 (pitch-66 broke this).
constexpr int PK = 72;

__device__ __forceinline__ ushort f2bf(float f) {   // RNE fp32 -> bf16
    unsigned u = __float_as_uint(f);
    u += 0x7FFF + ((u >> 16) & 1);
    return (ushort)(u >> 16);
}
__device__ __forceinline__ float bf2f(ushort u) {
    return __uint_as_float(((unsigned)u) << 16);
}
__device__ __forceinline__ unsigned cvt_pk_bf16(float lo, float hi) {
    unsigned r;
    asm("v_cvt_pk_bf16_f32 %0, %1, %2" : "=v"(r) : "v"(lo), "v"(hi));
    return r;
}
// pack 8 f32 -> 8 bf16 (RNE) with 4 instructions
__device__ __forceinline__ short8 pk8(float4 a, float4 b) {
    union { unsigned u[4]; short8 s; } r;
    r.u[0] = cvt_pk_bf16(a.x, a.y);
    r.u[1] = cvt_pk_bf16(a.z, a.w);
    r.u[2] = cvt_pk_bf16(b.x, b.y);
    r.u[3] = cvt_pk_bf16(b.z, b.w);
    return r.s;
}
// LDS-only barrier: orders ds ops across the block WITHOUT draining vmcnt,
// so register-prefetch global loads stay in flight across the barrier.
__device__ __forceinline__ void bar_lds() {
    asm volatile("s_waitcnt lgkmcnt(0)" ::: "memory");
    __builtin_amdgcn_s_barrier();
}

// -----------------------------------------------------------------------------
// Kernel 1: h = x @ Wq^T with FUSED f32->bf16 conversion (round-6 verified).
// BM=64 x BN=64, grid (64,12) = 768 blocks, 3/CU. Staging loads are f32
// float4 pairs, converted via v_cvt_pk_bf16_f32 at LDS-write time.
// -----------------------------------------------------------------------------
__global__ __launch_bounds__(256, 3)
void qkv_mfma(const float* __restrict__ x, const float* __restrict__ Wq,
              ushort* __restrict__ h)
{
    __shared__ ushort As[64 * PK];    // [row][k]
    __shared__ ushort Bs[64 * PK];    // [col][k]

    const int tid  = threadIdx.x;
    const int w    = tid >> 6;
    const int lane = tid & 63;
    const int m    = lane & 15;
    const int quad = lane >> 4;
    const int r0   = blockIdx.x * 64;
    const int c0   = blockIdx.y * 64;
    const int mrow0 = (w & 1) * 32;
    const int ncol0 = (w >> 1) * 32;

    floatx4 C[2][2] = {};
    float4 arf[2][2], brf[2][2];      // f32 prefetch (8 floats per id)

    #pragma unroll
    for (int i = 0; i < 2; ++i) {
        int id = tid + i * 256;
        const float* ax = x  + (size_t)(r0 + (id >> 3)) * DIN + (id & 7) * 8;
        const float* bx = Wq + (size_t)(c0 + (id >> 3)) * DIN + (id & 7) * 8;
        arf[i][0] = ((const float4*)ax)[0]; arf[i][1] = ((const float4*)ax)[1];
        brf[i][0] = ((const float4*)bx)[0]; brf[i][1] = ((const float4*)bx)[1];
    }

    for (int kk = 0; kk < 12; ++kk) {
        bar_lds();                      // prior reads consumed; no vmcnt drain
        #pragma unroll
        for (int i = 0; i < 2; ++i) {
            int id = tid + i * 256;
            *(short8*)&As[(id >> 3) * PK + (id & 7) * 8] = pk8(arf[i][0], arf[i][1]);
            *(short8*)&Bs[(id >> 3) * PK + (id & 7) * 8] = pk8(brf[i][0], brf[i][1]);
        }
        if (kk < 11) {                  // prefetch next tile (stays in flight)
            const int k0 = (kk + 1) * 64;
            #pragma unroll
            for (int i = 0; i < 2; ++i) {
                int id = tid + i * 256;
                const float* ax = x  + (size_t)(r0 + (id >> 3)) * DIN + k0 + (id & 7) * 8;
                const float* bx = Wq + (size_t)(c0 + (id >> 3)) * DIN + k0 + (id & 7) * 8;
                arf[i][0] = ((const float4*)ax)[0]; arf[i][1] = ((const float4*)ax)[1];
                brf[i][0] = ((const float4*)bx)[0]; brf[i][1] = ((const float4*)bx)[1];
            }
        }
        bar_lds();                      // writes visible; loads NOT drained

        #pragma unroll
        for (int kt2 = 0; kt2 < 2; ++kt2) {
            short8 a0 = *(const short8*)&As[(mrow0 + m)      * PK + kt2 * 32 + quad * 8];
            short8 a1 = *(const short8*)&As[(mrow0 + 16 + m) * PK + kt2 * 32 + quad * 8];
            short8 b0 = *(const short8*)&Bs[(ncol0 + m)      * PK + kt2 * 32 + quad * 8];
            short8 b1 = *(const short8*)&Bs[(ncol0 + 16 + m) * PK + kt2 * 32 + quad * 8];
            C[0][0] = MFMA16(a0, b0, C[0][0]);
            C[0][1] = MFMA16(a0, b1, C[0][1]);
            C[1][0] = MFMA16(a1, b0, C[1][0]);
            C[1][1] = MFMA16(a1, b1, C[1][1]);
        }
    }

    #pragma unroll
    for (int mt = 0; mt < 2; ++mt)
        #pragma unroll
        for (int nt = 0; nt < 2; ++nt) {
            int cg = c0 + ncol0 + nt * 16 + m;
            int head = cg >> 6, d = cg & 63;
            #pragma unroll
            for (int r = 0; r < 4; ++r) {
                int rg = r0 + mrow0 + mt * 16 + quad * 4 + r;
                int b = rg >> 11, q = rg & 2047;
                h[((size_t)(b * NH + head) * NSEQ + q) * 64 + d] = f2bf(C[mt][nt][r]);
            }
        }
}

// -----------------------------------------------------------------------------
// Kernel 2: causal flash attention — ROUND-3 verified structure (best measured:
// cooperative Ks/Vt staging = 1x L2 traffic; r6/r7's global-K = 3x L2 traffic
// and +30us). Block = 2 waves x 16 q; block owns complementary pair (qt,63-qt)
// -> exactly 33 k-tile units per block, grid (32,24) = 768 blocks, balanced
// under any dispatch order. bar_lds keeps prefetch loads in flight.
// NEW vs r3: s_setprio(1) around MFMA clusters (catalog m191: +4-7% on attn
// with independent blocks per CU at different phases).
// -----------------------------------------------------------------------------
__global__ __launch_bounds__(128, 3)
void attn_mfma(const ushort* __restrict__ h, float* __restrict__ out)
{
    __shared__ ushort Ks[64 * PK];      // [key][d]
    __shared__ ushort Vt[64 * PK];      // [d][key]
    __shared__ ushort Ps[2 * 16 * PK];  // per-wave P [q][key]

    const int tid  = threadIdx.x;
    const int w    = tid >> 6;          // 0..1
    const int lane = tid & 63;
    const int m    = lane & 15;
    const int quad = lane >> 4;

    const int p  = blockIdx.x;          // pair id 0..31
    const int bh = blockIdx.y;          // 0..23
    const ushort* __restrict__ Hh = h + (size_t)bh * NSEQ * 64;
    ushort* Psw = Ps + w * 16 * PK;

    const int kr2  = (tid & 31) * 2;    // staging: 2 adjacent key rows
    const int part = tid >> 5;          // d-chunk 0..3 (16 d each)
    const int db   = part * 16;

    #pragma unroll 1
    for (int half = 0; half < 2; ++half) {
        const int qt  = half ? p : (63 - p);
        const int q0  = qt * 32;
        const int wq  = q0 + w * 16;    // this wave's q base
        const int nkt = (qt >> 1) + 1;  // # of 64-key tiles

        // Q fragments (B-operand: n=q=m, k=d), pre-scaled by log2(e)/8
        short8 qa[2];
        #pragma unroll
        for (int kt2 = 0; kt2 < 2; ++kt2) {
            short8 raw = *(const short8*)(Hh + (size_t)(wq + m) * 64 + kt2 * 32 + quad * 8);
            #pragma unroll
            for (int j = 0; j < 8; ++j)
                qa[kt2][j] = (short)f2bf(bf2f((ushort)raw[j]) * QSCALE);
        }

        floatx4 O[4] = {};              // O^T tiles: d = mt*16+quad*4+r, q = m
        float lacc = 0.0f;

        short8 pre[4];                  // prefetched K rows kr2, kr2+1
        {
            const ushort* src = Hh + (size_t)kr2 * 64 + db;
            pre[0] = *(const short8*)src;
            pre[1] = *(const short8*)(src + 8);
            pre[2] = *(const short8*)(src + 64);
            pre[3] = *(const short8*)(src + 72);
        }

        for (int kt = 0; kt < nkt; ++kt) {
            bar_lds();                  // Ks/Vt free for overwrite (no vmcnt drain)
            *(short8*)&Ks[kr2       * PK + db]     = pre[0];
            *(short8*)&Ks[kr2       * PK + db + 8] = pre[1];
            *(short8*)&Ks[(kr2 + 1) * PK + db]     = pre[2];
            *(short8*)&Ks[(kr2 + 1) * PK + db + 8] = pre[3];
            union { short8 v; ushort u[8]; } a0, a1, b0, b1;
            a0.v = pre[0]; a1.v = pre[1]; b0.v = pre[2]; b1.v = pre[3];
            #pragma unroll
            for (int i = 0; i < 8; ++i) {
                *(unsigned*)&Vt[(db + i)     * PK + kr2] = (unsigned)a0.u[i] | ((unsigned)b0.u[i] << 16);
                *(unsigned*)&Vt[(db + 8 + i) * PK + kr2] = (unsigned)a1.u[i] | ((unsigned)b1.u[i] << 16);
            }
            if (kt + 1 < nkt) {         // prefetch next K tile (stays in flight)
                const ushort* src = Hh + (size_t)((kt + 1) * 64 + kr2) * 64 + db;
                pre[0] = *(const short8*)src;
                pre[1] = *(const short8*)(src + 8);
                pre[2] = *(const short8*)(src + 64);
                pre[3] = *(const short8*)(src + 72);
            }
            bar_lds();

            // ---- S^T = K Q^T : rows=key, cols=q ----
            floatx4 S[4] = {};
            __builtin_amdgcn_s_setprio(1);
            #pragma unroll
            for (int kt2 = 0; kt2 < 2; ++kt2)
                #pragma unroll
                for (int mt = 0; mt < 4; ++mt) {
                    short8 ka = *(const short8*)&Ks[(mt * 16 + m) * PK + kt2 * 32 + quad * 8];
                    S[mt] = MFMA16(ka, qa[kt2], S[mt]);
                }
            __builtin_amdgcn_s_setprio(0);

            // ---- exp2 + packed P write (cvt_pk) + l accumulate ----
            const int lim = wq + m - kt * 64;   // causal limit in-tile
            if (kt == nkt - 1) {                // diagonal tile: causal mask
                #pragma unroll
                for (int mt = 0; mt < 4; ++mt) {
                    float p0 = (mt * 16 + quad * 4 + 0 <= lim) ? exp2f(S[mt][0]) : 0.0f;
                    float p1 = (mt * 16 + quad * 4 + 1 <= lim) ? exp2f(S[mt][1]) : 0.0f;
                    float p2 = (mt * 16 + quad * 4 + 2 <= lim) ? exp2f(S[mt][2]) : 0.0f;
                    float p3 = (mt * 16 + quad * 4 + 3 <= lim) ? exp2f(S[mt][3]) : 0.0f;
                    lacc += (p0 + p1) + (p2 + p3);
                    uint2 pw;
                    pw.x = cvt_pk_bf16(p0, p1);
                    pw.y = cvt_pk_bf16(p2, p3);
                    *(uint2*)&Psw[m * PK + mt * 16 + quad * 4] = pw;
                }
            } else {                            // interior tile: no mask
                #pragma unroll
                for (int mt = 0; mt < 4; ++mt) {
                    float p0 = exp2f(S[mt][0]);
                    float p1 = exp2f(S[mt][1]);
                    float p2 = exp2f(S[mt][2]);
                    float p3 = exp2f(S[mt][3]);
                    lacc += (p0 + p1) + (p2 + p3);
                    uint2 pw;
                    pw.x = cvt_pk_bf16(p0, p1);
                    pw.y = cvt_pk_bf16(p2, p3);
                    *(uint2*)&Psw[m * PK + mt * 16 + quad * 4] = pw;
                }
            }

            // ---- O^T += V^T P^T (same-wave LDS, no barrier needed) ----
            __builtin_amdgcn_s_setprio(1);
            #pragma unroll
            for (int kt2 = 0; kt2 < 2; ++kt2) {
                short8 pb = *(const short8*)&Psw[m * PK + kt2 * 32 + quad * 8];
                #pragma unroll
                for (int mt = 0; mt < 4; ++mt) {
                    short8 va = *(const short8*)&Vt[(mt * 16 + m) * PK + kt2 * 32 + quad * 8];
                    O[mt] = MFMA16(va, pb, O[mt]);
                }
            }
            __builtin_amdgcn_s_setprio(0);
        }

        // ---- l reduce across the 4 quads holding the same q ----
        lacc += __shfl_xor(lacc, 16);
        lacc += __shfl_xor(lacc, 32);
        float linv = 1.0f / lacc;

        // ---- store out[bh][d][q] (reference's transposed layout) ----
        #pragma unroll
        for (int mt = 0; mt < 4; ++mt)
            #pragma unroll
            for (int r = 0; r < 4; ++r) {
                int d = mt * 16 + quad * 4 + r;
                out[((size_t)bh * 64 + d) * NSEQ + q0 + w * 16 + m] = O[mt][r] * linv;
            }
    }
}

extern "C" void kernel_launch(void* const* d_in, const int* in_sizes, int n_in,
                              void* d_out, int out_size, void* d_ws, size_t ws_size,
                              hipStream_t stream)
{
    (void)in_sizes; (void)n_in; (void)out_size; (void)ws_size;
    const float* x  = (const float*)d_in[0];
    const float* Wq = (const float*)d_in[1];
    float* out = (float*)d_out;

    ushort* hb = (ushort*)d_ws;                 // 6.29 MB (ws is 256 MiB)

    qkv_mfma<<<dim3(64, 12), dim3(256), 0, stream>>>(x, Wq, hb);
    attn_mfma<<<dim3(32, 24), dim3(128), 0, stream>>>(hb, out);
}

// Round 9
// 117.017 us; speedup vs baseline: 1.2799x; 1.0268x over previous
//
#include <hip/hip_runtime.h>
#include <math.h>

typedef __attribute__((ext_vector_type(8))) short  short8;    // 8 bf16 = 4 VGPRs
typedef __attribute__((ext_vector_type(4))) float  floatx4;   // MFMA C/D

#define MFMA16(a, b, c) __builtin_amdgcn_mfma_f32_16x16x32_bf16(a, b, c, 0, 0, 0)

constexpr int NSEQ = 2048;
constexpr int DIN  = 768;
constexpr int NH   = 12;
constexpr float QSCALE = 0.18033688011112042f;  // log2(e)/8

constexpr int PK = 72;   // 144 B rows, 16 B-aligned for b128

__device__ __forceinline__ ushort f2bf(float f) {   // RNE fp32 -> bf16
    unsigned u = __float_as_uint(f);
    u += 0x7FFF + ((u >> 16) & 1);
    return (ushort)(u >> 16);
}
__device__ __forceinline__ float bf2f(ushort u) {
    return __uint_as_float(((unsigned)u) << 16);
}
__device__ __forceinline__ unsigned cvt_pk_bf16(float lo, float hi) {
    unsigned r;
    asm("v_cvt_pk_bf16_f32 %0, %1, %2" : "=v"(r) : "v"(lo), "v"(hi));
    return r;
}
// pack 8 f32 -> 8 bf16 (RNE) with 4 instructions
__device__ __forceinline__ short8 pk8(float4 a, float4 b) {
    union { unsigned u[4]; short8 s; } r;
    r.u[0] = cvt_pk_bf16(a.x, a.y);
    r.u[1] = cvt_pk_bf16(a.z, a.w);
    r.u[2] = cvt_pk_bf16(b.x, b.y);
    r.u[3] = cvt_pk_bf16(b.z, b.w);
    return r.s;
}
// LDS-only barrier: orders ds ops across the block WITHOUT draining vmcnt,
// so register-prefetch global loads stay in flight across the barrier.
__device__ __forceinline__ void bar_lds() {
    asm volatile("s_waitcnt lgkmcnt(0)" ::: "memory");
    __builtin_amdgcn_s_barrier();
}

// -----------------------------------------------------------------------------
// Kernel 1: h = x @ Wq^T with FUSED f32->bf16 conversion (r6/r8 verified).
// BM=64 x BN=64, grid (64,12) = 768 blocks, 3/CU.
// -----------------------------------------------------------------------------
__global__ __launch_bounds__(256, 3)
void qkv_mfma(const float* __restrict__ x, const float* __restrict__ Wq,
              ushort* __restrict__ h)
{
    __shared__ ushort As[64 * PK];    // [row][k]
    __shared__ ushort Bs[64 * PK];    // [col][k]

    const int tid  = threadIdx.x;
    const int w    = tid >> 6;
    const int lane = tid & 63;
    const int m    = lane & 15;
    const int quad = lane >> 4;
    const int r0   = blockIdx.x * 64;
    const int c0   = blockIdx.y * 64;
    const int mrow0 = (w & 1) * 32;
    const int ncol0 = (w >> 1) * 32;

    floatx4 C[2][2] = {};
    float4 arf[2][2], brf[2][2];      // f32 prefetch (8 floats per id)

    #pragma unroll
    for (int i = 0; i < 2; ++i) {
        int id = tid + i * 256;
        const float* ax = x  + (size_t)(r0 + (id >> 3)) * DIN + (id & 7) * 8;
        const float* bx = Wq + (size_t)(c0 + (id >> 3)) * DIN + (id & 7) * 8;
        arf[i][0] = ((const float4*)ax)[0]; arf[i][1] = ((const float4*)ax)[1];
        brf[i][0] = ((const float4*)bx)[0]; brf[i][1] = ((const float4*)bx)[1];
    }

    for (int kk = 0; kk < 12; ++kk) {
        bar_lds();                      // prior reads consumed; no vmcnt drain
        #pragma unroll
        for (int i = 0; i < 2; ++i) {
            int id = tid + i * 256;
            *(short8*)&As[(id >> 3) * PK + (id & 7) * 8] = pk8(arf[i][0], arf[i][1]);
            *(short8*)&Bs[(id >> 3) * PK + (id & 7) * 8] = pk8(brf[i][0], brf[i][1]);
        }
        if (kk < 11) {                  // prefetch next tile (stays in flight)
            const int k0 = (kk + 1) * 64;
            #pragma unroll
            for (int i = 0; i < 2; ++i) {
                int id = tid + i * 256;
                const float* ax = x  + (size_t)(r0 + (id >> 3)) * DIN + k0 + (id & 7) * 8;
                const float* bx = Wq + (size_t)(c0 + (id >> 3)) * DIN + k0 + (id & 7) * 8;
                arf[i][0] = ((const float4*)ax)[0]; arf[i][1] = ((const float4*)ax)[1];
                brf[i][0] = ((const float4*)bx)[0]; brf[i][1] = ((const float4*)bx)[1];
            }
        }
        bar_lds();                      // writes visible; loads NOT drained

        #pragma unroll
        for (int kt2 = 0; kt2 < 2; ++kt2) {
            short8 a0 = *(const short8*)&As[(mrow0 + m)      * PK + kt2 * 32 + quad * 8];
            short8 a1 = *(const short8*)&As[(mrow0 + 16 + m) * PK + kt2 * 32 + quad * 8];
            short8 b0 = *(const short8*)&Bs[(ncol0 + m)      * PK + kt2 * 32 + quad * 8];
            short8 b1 = *(const short8*)&Bs[(ncol0 + 16 + m) * PK + kt2 * 32 + quad * 8];
            C[0][0] = MFMA16(a0, b0, C[0][0]);
            C[0][1] = MFMA16(a0, b1, C[0][1]);
            C[1][0] = MFMA16(a1, b0, C[1][0]);
            C[1][1] = MFMA16(a1, b1, C[1][1]);
        }
    }

    #pragma unroll
    for (int mt = 0; mt < 2; ++mt)
        #pragma unroll
        for (int nt = 0; nt < 2; ++nt) {
            int cg = c0 + ncol0 + nt * 16 + m;
            int head = cg >> 6, d = cg & 63;
            #pragma unroll
            for (int r = 0; r < 4; ++r) {
                int rg = r0 + mrow0 + mt * 16 + quad * 4 + r;
                int b = rg >> 11, q = rg & 2047;
                h[((size_t)(b * NH + head) * NSEQ + q) * 64 + d] = f2bf(C[mt][nt][r]);
            }
        }
}

// -----------------------------------------------------------------------------
// Kernel 2: causal flash attention — 4-WAVE pair-blocks (latency fix).
// Diagnosis (r8 counters): no pipe >30%, 1.5 waves/SIMD, ~2.2K-cyc serial chain
// per wave-iteration -> latency-bound. Fix: 256-thr blocks; waves split each
// 64-key tile by (q-subtile x key-half): wave w -> qsub=w&1, khalf=w>>1.
// Per wave-iter: 4 S-MFMA + 8 exp2 + 4 PV-MFMA (half the old chain), and
// 12 waves/CU = 3/SIMD (was 6 = 1.5/SIMD). Key-half O/l partials merged once
// per pair-half via LDS scratch. Ks/Vt double-buffered (41 KB, 3 blocks/CU)
// -> ONE bar_lds per iteration; staging after compute; prefetch 1 tile ahead.
// 8-way d-chunk staging makes every LDS op conflict-free (bank-audited).
// Pair mapping (qt, 63-qt): exactly 33 tile-units per block. No setprio
// (r8: hurt in lockstep blocks).
// -----------------------------------------------------------------------------
__global__ __launch_bounds__(256, 3)
void attn_mfma(const ushort* __restrict__ h, float* __restrict__ out)
{
    __shared__ ushort Ks[2][64 * PK];   // [buf][key][d]
    __shared__ ushort Vt[2][64 * PK];   // [buf][d][key]
    __shared__ ushort Ps[2][16 * PK];   // [qsub][q][key]

    const int tid  = threadIdx.x;
    const int w    = tid >> 6;          // 0..3
    const int lane = tid & 63;
    const int m    = lane & 15;
    const int quad = lane >> 4;
    const int qsub = w & 1;             // q-subtile 0/1 (16 q each)
    const int khalf= w >> 1;            // key-half 0/1 (32 keys each)

    const int p  = blockIdx.x;          // pair id 0..31
    const int bh = blockIdx.y;          // 0..23
    const ushort* __restrict__ Hh = h + (size_t)bh * NSEQ * 64;
    ushort* Psw = Ps[qsub];

    const int kr2  = (tid & 31) * 2;    // staging: 2 adjacent key rows
    const int part = tid >> 5;          // d-chunk 0..7 (8 d each)
    const int db   = part * 8;

    float* Om = (float*)&Ks[0][0];      // merge scratch [2][64][pitch 17]
    float* Lm = Om + 2 * 64 * 17;       // [2][16]

    #pragma unroll 1
    for (int half = 0; half < 2; ++half) {
        if (half) bar_lds();            // scratch reads done before restaging

        const int qt  = half ? p : (63 - p);
        const int q0  = qt * 32;
        const int wq  = q0 + qsub * 16; // this wave's q base
        const int nkt = (qt >> 1) + 1;  // # of 64-key tiles

        // Q fragments (B-operand: n=q=m, k=d), pre-scaled by log2(e)/8
        short8 qa[2];
        #pragma unroll
        for (int kt2 = 0; kt2 < 2; ++kt2) {
            short8 raw = *(const short8*)(Hh + (size_t)(wq + m) * 64 + kt2 * 32 + quad * 8);
            #pragma unroll
            for (int j = 0; j < 8; ++j)
                qa[kt2][j] = (short)f2bf(bf2f((ushort)raw[j]) * QSCALE);
        }

        floatx4 O[4] = {};              // O^T partial (khalf keys): d=mt*16+quad*4+r, q=m
        float lacc = 0.0f;

        short8 pre0, pre1;              // prefetched K rows kr2, kr2+1 (8 d each)
        {
            const ushort* src = Hh + (size_t)kr2 * 64 + db;
            pre0 = *(const short8*)src;
            pre1 = *(const short8*)(src + 64);
        }
        // stage tile 0 into buf0
        {
            *(short8*)&Ks[0][kr2       * PK + db] = pre0;
            *(short8*)&Ks[0][(kr2 + 1) * PK + db] = pre1;
            union { short8 v; ushort u[8]; } ua, ub;
            ua.v = pre0; ub.v = pre1;
            #pragma unroll
            for (int i = 0; i < 8; ++i)
                *(unsigned*)&Vt[0][(db + i) * PK + kr2] =
                    (unsigned)ua.u[i] | ((unsigned)ub.u[i] << 16);
        }
        if (nkt > 1) {                  // prefetch tile 1 (in flight across bar)
            const ushort* src = Hh + (size_t)(64 + kr2) * 64 + db;
            pre0 = *(const short8*)src;
            pre1 = *(const short8*)(src + 64);
        }
        bar_lds();

        for (int kt = 0; kt < nkt; ++kt) {
            const int cur = kt & 1;

            // ---- S^T = K Q^T : this wave's 32 keys (khalf) x its 16 q ----
            floatx4 S[2] = {};
            #pragma unroll
            for (int kt2 = 0; kt2 < 2; ++kt2)
                #pragma unroll
                for (int mt2 = 0; mt2 < 2; ++mt2) {
                    short8 ka = *(const short8*)
                        &Ks[cur][(khalf * 32 + mt2 * 16 + m) * PK + kt2 * 32 + quad * 8];
                    S[mt2] = MFMA16(ka, qa[kt2], S[mt2]);
                }

            // ---- exp2 + packed P write + l accumulate (own key-half) ----
            const int lim  = wq + m - kt * 64;
            const bool diag = (kt == nkt - 1);
            #pragma unroll
            for (int mt2 = 0; mt2 < 2; ++mt2) {
                const int kb = (khalf * 2 + mt2) * 16 + quad * 4;   // key-in-tile base
                float p0, p1, p2, p3;
                if (diag) {
                    p0 = (kb + 0 <= lim) ? exp2f(S[mt2][0]) : 0.0f;
                    p1 = (kb + 1 <= lim) ? exp2f(S[mt2][1]) : 0.0f;
                    p2 = (kb + 2 <= lim) ? exp2f(S[mt2][2]) : 0.0f;
                    p3 = (kb + 3 <= lim) ? exp2f(S[mt2][3]) : 0.0f;
                } else {
                    p0 = exp2f(S[mt2][0]);
                    p1 = exp2f(S[mt2][1]);
                    p2 = exp2f(S[mt2][2]);
                    p3 = exp2f(S[mt2][3]);
                }
                lacc += (p0 + p1) + (p2 + p3);
                uint2 pw;
                pw.x = cvt_pk_bf16(p0, p1);
                pw.y = cvt_pk_bf16(p2, p3);
                *(uint2*)&Psw[m * PK + kb] = pw;
            }

            // ---- O^T += V^T P^T over own 32 keys: 4 MFMAs (k=32) ----
            short8 pb = *(const short8*)&Psw[m * PK + khalf * 32 + quad * 8];
            #pragma unroll
            for (int mt = 0; mt < 4; ++mt) {
                short8 va = *(const short8*)
                    &Vt[cur][(mt * 16 + m) * PK + khalf * 32 + quad * 8];
                O[mt] = MFMA16(va, pb, O[mt]);
            }

            // ---- stage next tile into alternate buffer; prefetch kt+2 ----
            if (kt + 1 < nkt) {
                const int nxt = cur ^ 1;
                *(short8*)&Ks[nxt][kr2       * PK + db] = pre0;
                *(short8*)&Ks[nxt][(kr2 + 1) * PK + db] = pre1;
                union { short8 v; ushort u[8]; } ua, ub;
                ua.v = pre0; ub.v = pre1;
                #pragma unroll
                for (int i = 0; i < 8; ++i)
                    *(unsigned*)&Vt[nxt][(db + i) * PK + kr2] =
                        (unsigned)ua.u[i] | ((unsigned)ub.u[i] << 16);
                if (kt + 2 < nkt) {
                    const ushort* src = Hh + (size_t)((kt + 2) * 64 + kr2) * 64 + db;
                    pre0 = *(const short8*)src;
                    pre1 = *(const short8*)(src + 64);
                }
            }
            bar_lds();                  // ONE barrier per iteration
        }

        // ---- merge key-half partials ----
        lacc += __shfl_xor(lacc, 16);
        lacc += __shfl_xor(lacc, 32);
        if (khalf == 1) {
            #pragma unroll
            for (int mt = 0; mt < 4; ++mt)
                #pragma unroll
                for (int r = 0; r < 4; ++r) {
                    int d = mt * 16 + quad * 4 + r;
                    Om[(qsub * 64 + d) * 17 + m] = O[mt][r];
                }
            if (quad == 0) Lm[qsub * 16 + m] = lacc;
        }
        bar_lds();
        if (khalf == 0) {
            float linv = 1.0f / (lacc + Lm[qsub * 16 + m]);
            #pragma unroll
            for (int mt = 0; mt < 4; ++mt)
                #pragma unroll
                for (int r = 0; r < 4; ++r) {
                    int d = mt * 16 + quad * 4 + r;
                    float v = O[mt][r] + Om[(qsub * 64 + d) * 17 + m];
                    out[((size_t)bh * 64 + d) * NSEQ + q0 + qsub * 16 + m] = v * linv;
                }
        }
    }
}

extern "C" void kernel_launch(void* const* d_in, const int* in_sizes, int n_in,
                              void* d_out, int out_size, void* d_ws, size_t ws_size,
                              hipStream_t stream)
{
    (void)in_sizes; (void)n_in; (void)out_size; (void)ws_size;
    const float* x  = (const float*)d_in[0];
    const float* Wq = (const float*)d_in[1];
    float* out = (float*)d_out;

    ushort* hb = (ushort*)d_ws;                 // 6.29 MB (ws is 256 MiB)

    qkv_mfma<<<dim3(64, 12), dim3(256), 0, stream>>>(x, Wq, hb);
    attn_mfma<<<dim3(32, 24), dim3(256), 0, stream>>>(hb, out);
}

// Round 10
// 114.939 us; speedup vs baseline: 1.3030x; 1.0181x over previous
//
#include <hip/hip_runtime.h>
#include <math.h>

typedef __attribute__((ext_vector_type(8))) short  short8;    // 8 bf16 = 4 VGPRs
typedef __attribute__((ext_vector_type(4))) float  floatx4;   // MFMA C/D

#define MFMA16(a, b, c) __builtin_amdgcn_mfma_f32_16x16x32_bf16(a, b, c, 0, 0, 0)

constexpr int NSEQ = 2048;
constexpr int DIN  = 768;
constexpr int NH   = 12;
constexpr float QSCALE = 0.18033688011112042f;  // log2(e)/8

constexpr int PK = 72;   // 144 B rows, 16 B-aligned for b128

__device__ __forceinline__ ushort f2bf(float f) {   // RNE fp32 -> bf16
    unsigned u = __float_as_uint(f);
    u += 0x7FFF + ((u >> 16) & 1);
    return (ushort)(u >> 16);
}
__device__ __forceinline__ float bf2f(ushort u) {
    return __uint_as_float(((unsigned)u) << 16);
}
__device__ __forceinline__ unsigned cvt_pk_bf16(float lo, float hi) {
    unsigned r;
    asm("v_cvt_pk_bf16_f32 %0, %1, %2" : "=v"(r) : "v"(lo), "v"(hi));
    return r;
}
// pack 8 f32 -> 8 bf16 (RNE) with 4 instructions
__device__ __forceinline__ short8 pk8(float4 a, float4 b) {
    union { unsigned u[4]; short8 s; } r;
    r.u[0] = cvt_pk_bf16(a.x, a.y);
    r.u[1] = cvt_pk_bf16(a.z, a.w);
    r.u[2] = cvt_pk_bf16(b.x, b.y);
    r.u[3] = cvt_pk_bf16(b.z, b.w);
    return r.s;
}
// LDS-only barrier: orders ds ops across the block WITHOUT draining vmcnt,
// so register-prefetch global loads stay in flight across the barrier.
__device__ __forceinline__ void bar_lds() {
    asm volatile("s_waitcnt lgkmcnt(0)" ::: "memory");
    __builtin_amdgcn_s_barrier();
}

// -----------------------------------------------------------------------------
// Kernel 1: h = x @ Wq^T, fused f32->bf16, DOUBLE-BUFFERED LDS.
// BM=64 x BN=64, grid (64,12) = 768 blocks, 3/CU (LDS 36.9 KB -> still 3/CU).
// Per k-iter: compute buf[cur] || stage buf[cur^1] from regs || prefetch kk+2,
// then ONE bar_lds (was 2 barriers + serialized stage->compute). The stage's
// vmcnt wait targets loads issued a full iteration earlier -> latency hidden.
// -----------------------------------------------------------------------------
__global__ __launch_bounds__(256, 3)
void qkv_mfma(const float* __restrict__ x, const float* __restrict__ Wq,
              ushort* __restrict__ h)
{
    __shared__ ushort As[2][64 * PK];    // [buf][row][k]
    __shared__ ushort Bs[2][64 * PK];    // [buf][col][k]

    const int tid  = threadIdx.x;
    const int w    = tid >> 6;
    const int lane = tid & 63;
    const int m    = lane & 15;
    const int quad = lane >> 4;
    const int r0   = blockIdx.x * 64;
    const int c0   = blockIdx.y * 64;
    const int mrow0 = (w & 1) * 32;
    const int ncol0 = (w >> 1) * 32;

    const int srow = tid >> 3;          // staging row 0..31 (+32 for i=1)
    const int scol = (tid & 7) * 8;     // staging col (8 floats)

    floatx4 C[2][2] = {};
    float4 arf[2][2], brf[2][2];        // f32 prefetch regs (8 floats per i)

    // ---- load tile 0 ----
    #pragma unroll
    for (int i = 0; i < 2; ++i) {
        const float* ax = x  + (size_t)(r0 + srow + i * 32) * DIN + scol;
        const float* bx = Wq + (size_t)(c0 + srow + i * 32) * DIN + scol;
        arf[i][0] = ((const float4*)ax)[0]; arf[i][1] = ((const float4*)ax)[1];
        brf[i][0] = ((const float4*)bx)[0]; brf[i][1] = ((const float4*)bx)[1];
    }
    // ---- stage tile 0 into buf0 ----
    #pragma unroll
    for (int i = 0; i < 2; ++i) {
        *(short8*)&As[0][(srow + i * 32) * PK + scol] = pk8(arf[i][0], arf[i][1]);
        *(short8*)&Bs[0][(srow + i * 32) * PK + scol] = pk8(brf[i][0], brf[i][1]);
    }
    // ---- prefetch tile 1 (stays in flight across the barrier) ----
    #pragma unroll
    for (int i = 0; i < 2; ++i) {
        const float* ax = x  + (size_t)(r0 + srow + i * 32) * DIN + 64 + scol;
        const float* bx = Wq + (size_t)(c0 + srow + i * 32) * DIN + 64 + scol;
        arf[i][0] = ((const float4*)ax)[0]; arf[i][1] = ((const float4*)ax)[1];
        brf[i][0] = ((const float4*)bx)[0]; brf[i][1] = ((const float4*)bx)[1];
    }
    bar_lds();

    for (int kk = 0; kk < 12; ++kk) {
        const int cur = kk & 1;

        // ---- compute from buf[cur] ----
        #pragma unroll
        for (int kt2 = 0; kt2 < 2; ++kt2) {
            short8 a0 = *(const short8*)&As[cur][(mrow0 + m)      * PK + kt2 * 32 + quad * 8];
            short8 a1 = *(const short8*)&As[cur][(mrow0 + 16 + m) * PK + kt2 * 32 + quad * 8];
            short8 b0 = *(const short8*)&Bs[cur][(ncol0 + m)      * PK + kt2 * 32 + quad * 8];
            short8 b1 = *(const short8*)&Bs[cur][(ncol0 + 16 + m) * PK + kt2 * 32 + quad * 8];
            C[0][0] = MFMA16(a0, b0, C[0][0]);
            C[0][1] = MFMA16(a0, b1, C[0][1]);
            C[1][0] = MFMA16(a1, b0, C[1][0]);
            C[1][1] = MFMA16(a1, b1, C[1][1]);
        }

        if (kk + 1 < 12) {
            // ---- stage next tile into alternate buffer (regs hold tile kk+1) ----
            const int nxt = cur ^ 1;
            #pragma unroll
            for (int i = 0; i < 2; ++i) {
                *(short8*)&As[nxt][(srow + i * 32) * PK + scol] = pk8(arf[i][0], arf[i][1]);
                *(short8*)&Bs[nxt][(srow + i * 32) * PK + scol] = pk8(brf[i][0], brf[i][1]);
            }
            // ---- prefetch tile kk+2 ----
            if (kk + 2 < 12) {
                const int k0 = (kk + 2) * 64;
                #pragma unroll
                for (int i = 0; i < 2; ++i) {
                    const float* ax = x  + (size_t)(r0 + srow + i * 32) * DIN + k0 + scol;
                    const float* bx = Wq + (size_t)(c0 + srow + i * 32) * DIN + k0 + scol;
                    arf[i][0] = ((const float4*)ax)[0]; arf[i][1] = ((const float4*)ax)[1];
                    brf[i][0] = ((const float4*)bx)[0]; brf[i][1] = ((const float4*)bx)[1];
                }
            }
            bar_lds();                  // ONE barrier per iteration
        }
    }

    #pragma unroll
    for (int mt = 0; mt < 2; ++mt)
        #pragma unroll
        for (int nt = 0; nt < 2; ++nt) {
            int cg = c0 + ncol0 + nt * 16 + m;
            int head = cg >> 6, d = cg & 63;
            #pragma unroll
            for (int r = 0; r < 4; ++r) {
                int rg = r0 + mrow0 + mt * 16 + quad * 4 + r;
                int b = rg >> 11, q = rg & 2047;
                h[((size_t)(b * NH + head) * NSEQ + q) * 64 + d] = f2bf(C[mt][nt][r]);
            }
        }
}

// -----------------------------------------------------------------------------
// Kernel 2: causal flash attention — 4-WAVE pair-blocks (round-9 verified,
// best measured: 43.5 us, occupancy 23%). UNCHANGED this round.
// -----------------------------------------------------------------------------
__global__ __launch_bounds__(256, 3)
void attn_mfma(const ushort* __restrict__ h, float* __restrict__ out)
{
    __shared__ ushort Ks[2][64 * PK];   // [buf][key][d]
    __shared__ ushort Vt[2][64 * PK];   // [buf][d][key]
    __shared__ ushort Ps[2][16 * PK];   // [qsub][q][key]

    const int tid  = threadIdx.x;
    const int w    = tid >> 6;          // 0..3
    const int lane = tid & 63;
    const int m    = lane & 15;
    const int quad = lane >> 4;
    const int qsub = w & 1;             // q-subtile 0/1 (16 q each)
    const int khalf= w >> 1;            // key-half 0/1 (32 keys each)

    const int p  = blockIdx.x;          // pair id 0..31
    const int bh = blockIdx.y;          // 0..23
    const ushort* __restrict__ Hh = h + (size_t)bh * NSEQ * 64;
    ushort* Psw = Ps[qsub];

    const int kr2  = (tid & 31) * 2;    // staging: 2 adjacent key rows
    const int part = tid >> 5;          // d-chunk 0..7 (8 d each)
    const int db   = part * 8;

    float* Om = (float*)&Ks[0][0];      // merge scratch [2][64][pitch 17]
    float* Lm = Om + 2 * 64 * 17;       // [2][16]

    #pragma unroll 1
    for (int half = 0; half < 2; ++half) {
        if (half) bar_lds();            // scratch reads done before restaging

        const int qt  = half ? p : (63 - p);
        const int q0  = qt * 32;
        const int wq  = q0 + qsub * 16; // this wave's q base
        const int nkt = (qt >> 1) + 1;  // # of 64-key tiles

        // Q fragments (B-operand: n=q=m, k=d), pre-scaled by log2(e)/8
        short8 qa[2];
        #pragma unroll
        for (int kt2 = 0; kt2 < 2; ++kt2) {
            short8 raw = *(const short8*)(Hh + (size_t)(wq + m) * 64 + kt2 * 32 + quad * 8);
            #pragma unroll
            for (int j = 0; j < 8; ++j)
                qa[kt2][j] = (short)f2bf(bf2f((ushort)raw[j]) * QSCALE);
        }

        floatx4 O[4] = {};              // O^T partial (khalf keys): d=mt*16+quad*4+r, q=m
        float lacc = 0.0f;

        short8 pre0, pre1;              // prefetched K rows kr2, kr2+1 (8 d each)
        {
            const ushort* src = Hh + (size_t)kr2 * 64 + db;
            pre0 = *(const short8*)src;
            pre1 = *(const short8*)(src + 64);
        }
        // stage tile 0 into buf0
        {
            *(short8*)&Ks[0][kr2       * PK + db] = pre0;
            *(short8*)&Ks[0][(kr2 + 1) * PK + db] = pre1;
            union { short8 v; ushort u[8]; } ua, ub;
            ua.v = pre0; ub.v = pre1;
            #pragma unroll
            for (int i = 0; i < 8; ++i)
                *(unsigned*)&Vt[0][(db + i) * PK + kr2] =
                    (unsigned)ua.u[i] | ((unsigned)ub.u[i] << 16);
        }
        if (nkt > 1) {                  // prefetch tile 1 (in flight across bar)
            const ushort* src = Hh + (size_t)(64 + kr2) * 64 + db;
            pre0 = *(const short8*)src;
            pre1 = *(const short8*)(src + 64);
        }
        bar_lds();

        for (int kt = 0; kt < nkt; ++kt) {
            const int cur = kt & 1;

            // ---- S^T = K Q^T : this wave's 32 keys (khalf) x its 16 q ----
            floatx4 S[2] = {};
            #pragma unroll
            for (int kt2 = 0; kt2 < 2; ++kt2)
                #pragma unroll
                for (int mt2 = 0; mt2 < 2; ++mt2) {
                    short8 ka = *(const short8*)
                        &Ks[cur][(khalf * 32 + mt2 * 16 + m) * PK + kt2 * 32 + quad * 8];
                    S[mt2] = MFMA16(ka, qa[kt2], S[mt2]);
                }

            // ---- exp2 + packed P write + l accumulate (own key-half) ----
            const int lim  = wq + m - kt * 64;
            const bool diag = (kt == nkt - 1);
            #pragma unroll
            for (int mt2 = 0; mt2 < 2; ++mt2) {
                const int kb = (khalf * 2 + mt2) * 16 + quad * 4;   // key-in-tile base
                float p0, p1, p2, p3;
                if (diag) {
                    p0 = (kb + 0 <= lim) ? exp2f(S[mt2][0]) : 0.0f;
                    p1 = (kb + 1 <= lim) ? exp2f(S[mt2][1]) : 0.0f;
                    p2 = (kb + 2 <= lim) ? exp2f(S[mt2][2]) : 0.0f;
                    p3 = (kb + 3 <= lim) ? exp2f(S[mt2][3]) : 0.0f;
                } else {
                    p0 = exp2f(S[mt2][0]);
                    p1 = exp2f(S[mt2][1]);
                    p2 = exp2f(S[mt2][2]);
                    p3 = exp2f(S[mt2][3]);
                }
                lacc += (p0 + p1) + (p2 + p3);
                uint2 pw;
                pw.x = cvt_pk_bf16(p0, p1);
                pw.y = cvt_pk_bf16(p2, p3);
                *(uint2*)&Psw[m * PK + kb] = pw;
            }

            // ---- O^T += V^T P^T over own 32 keys: 4 MFMAs (k=32) ----
            short8 pb = *(const short8*)&Psw[m * PK + khalf * 32 + quad * 8];
            #pragma unroll
            for (int mt = 0; mt < 4; ++mt) {
                short8 va = *(const short8*)
                    &Vt[cur][(mt * 16 + m) * PK + khalf * 32 + quad * 8];
                O[mt] = MFMA16(va, pb, O[mt]);
            }

            // ---- stage next tile into alternate buffer; prefetch kt+2 ----
            if (kt + 1 < nkt) {
                const int nxt = cur ^ 1;
                *(short8*)&Ks[nxt][kr2       * PK + db] = pre0;
                *(short8*)&Ks[nxt][(kr2 + 1) * PK + db] = pre1;
                union { short8 v; ushort u[8]; } ua, ub;
                ua.v = pre0; ub.v = pre1;
                #pragma unroll
                for (int i = 0; i < 8; ++i)
                    *(unsigned*)&Vt[nxt][(db + i) * PK + kr2] =
                        (unsigned)ua.u[i] | ((unsigned)ub.u[i] << 16);
                if (kt + 2 < nkt) {
                    const ushort* src = Hh + (size_t)((kt + 2) * 64 + kr2) * 64 + db;
                    pre0 = *(const short8*)src;
                    pre1 = *(const short8*)(src + 64);
                }
            }
            bar_lds();                  // ONE barrier per iteration
        }

        // ---- merge key-half partials ----
        lacc += __shfl_xor(lacc, 16);
        lacc += __shfl_xor(lacc, 32);
        if (khalf == 1) {
            #pragma unroll
            for (int mt = 0; mt < 4; ++mt)
                #pragma unroll
                for (int r = 0; r < 4; ++r) {
                    int d = mt * 16 + quad * 4 + r;
                    Om[(qsub * 64 + d) * 17 + m] = O[mt][r];
                }
            if (quad == 0) Lm[qsub * 16 + m] = lacc;
        }
        bar_lds();
        if (khalf == 0) {
            float linv = 1.0f / (lacc + Lm[qsub * 16 + m]);
            #pragma unroll
            for (int mt = 0; mt < 4; ++mt)
                #pragma unroll
                for (int r = 0; r < 4; ++r) {
                    int d = mt * 16 + quad * 4 + r;
                    float v = O[mt][r] + Om[(qsub * 64 + d) * 17 + m];
                    out[((size_t)bh * 64 + d) * NSEQ + q0 + qsub * 16 + m] = v * linv;
                }
        }
    }
}

extern "C" void kernel_launch(void* const* d_in, const int* in_sizes, int n_in,
                              void* d_out, int out_size, void* d_ws, size_t ws_size,
                              hipStream_t stream)
{
    (void)in_sizes; (void)n_in; (void)out_size; (void)ws_size;
    const float* x  = (const float*)d_in[0];
    const float* Wq = (const float*)d_in[1];
    float* out = (float*)d_out;

    ushort* hb = (ushort*)d_ws;                 // 6.29 MB (ws is 256 MiB)

    qkv_mfma<<<dim3(64, 12), dim3(256), 0, stream>>>(x, Wq, hb);
    attn_mfma<<<dim3(32, 24), dim3(256), 0, stream>>>(hb, out);
}